// Round 3
// baseline (686.337 us; speedup 1.0000x reference)
//
#include <hip/hip_runtime.h>

// Problem constants
#define BB 256      // batch
#define VV 50257    // per-model vocab
#define UU 65536    // union vocab
#define MM 3        // models
#define TILE 16     // u-tile width (union slots per accumulate block)
#define NT 4096     // u-tiles (UU / TILE)

typedef float float4a __attribute__((ext_vector_type(4), aligned(4)));
typedef _Float16 half4v __attribute__((ext_vector_type(4)));

// ---------------------------------------------------------------------------
// FAST-PATH workspace layout (bytes):
//   0      : Z      [3*256] float  (softmax denominators; memset 0 each call)
//   3072   : hist   [4096]  int    (memset 0 each call)
//   19456  : off    [4097]  int
//   35856  : cursor [4096]  int    (16-aligned for int4 stores)
//   52240  : sorted [150771] int   (packed (j<<8)|(m<<6)|(u&15))
//   655360 : ET     [3][50257][256] fp16  (77,194,752 B)
// total 77,850,112 B
// ---------------------------------------------------------------------------
#define WS_Z      0
#define WS_HIST   3072
#define WS_OFF    19456
#define WS_CURSOR 35856
#define WS_SORTED 52240
#define WS_ET     655360
#define WS_NEED   77850112ull

// ---------------------------------------------------------------------------
// winv[m*B+b] = w_m / sum_j exp(logits[m][b][j]).  FALLBACK PATH ONLY.
// ---------------------------------------------------------------------------
__global__ __launch_bounds__(512) void row_sums_kernel(
    const float* __restrict__ l0, const float* __restrict__ l1,
    const float* __restrict__ l2, const float* __restrict__ weights,
    float* __restrict__ winv)
{
    const int bx = blockIdx.x;            // [0, MM*BB)
    const int m  = bx >> 8;
    const int b  = bx & 255;
    const float* lg  = (m == 0) ? l0 : (m == 1) ? l1 : l2;
    const float* row = lg + (size_t)b * VV;
    const float4a* rowv = (const float4a*)row;

    const int nv4 = VV / 4;               // 12564, tail element j=50256
    float partial = 0.0f;
    for (int i = threadIdx.x; i < nv4; i += 512) {
        float4a v = rowv[i];
        partial += __expf(v.x) + __expf(v.y) + __expf(v.z) + __expf(v.w);
    }
    if (threadIdx.x == 0) partial += __expf(row[VV - 1]);

    #pragma unroll
    for (int off = 32; off > 0; off >>= 1)
        partial += __shfl_down(partial, off, 64);

    __shared__ float smem[8];
    const int lane = threadIdx.x & 63;
    const int wv   = threadIdx.x >> 6;
    if (lane == 0) smem[wv] = partial;
    __syncthreads();
    if (threadIdx.x == 0) {
        float tot = 0.0f;
        #pragma unroll
        for (int w = 0; w < 8; ++w) tot += smem[w];
        winv[bx] = weights[m] / tot;
    }
}

// ---------------------------------------------------------------------------
// u-tile histogram over all 3 maps.  Direct global int atomics (native
// global_atomic_add_u32): 150,771 atomics over 4096 bins ~ 37/bin.
// ---------------------------------------------------------------------------
__global__ __launch_bounds__(256) void hist_count_kernel(
    const int* __restrict__ m0, const int* __restrict__ m1,
    const int* __restrict__ m2, int* __restrict__ hist)
{
    const int total = MM * VV;
    for (int idx = blockIdx.x * 256 + threadIdx.x; idx < total;
         idx += gridDim.x * 256) {
        const int m = idx / VV;           // const divisor -> magic mul
        const int j = idx - m * VV;
        const int* mp = (m == 0) ? m0 : (m == 1) ? m1 : m2;
        atomicAdd(&hist[mp[j] >> 4], 1);
    }
}

// ---------------------------------------------------------------------------
// Single-block exclusive scan over 4096 bins.
// v2: shfl wave-scan (6 steps) + 16-wave-sum scan -> 2 barriers total
// (was Hillis-Steele with 20 barriers; this block serializes the GPU).
// ---------------------------------------------------------------------------
__global__ __launch_bounds__(1024) void prefix_kernel(
    const int* __restrict__ hist, int* __restrict__ off, int* __restrict__ cursor)
{
    __shared__ int wsum[16];
    const int t = threadIdx.x;
    const int l = t & 63, wv = t >> 6;
    const int4 h = ((const int4*)hist)[t];        // bins 4t..4t+3
    const int sum = h.x + h.y + h.z + h.w;

    // inclusive wave scan of per-thread sums
    int sc = sum;
    #pragma unroll
    for (int d = 1; d < 64; d <<= 1) {
        const int v = __shfl_up(sc, d, 64);
        if (l >= d) sc += v;
    }
    if (l == 63) wsum[wv] = sc;
    __syncthreads();
    if (t < 16) {
        const int ws = wsum[t];
        int wsc = ws;
        #pragma unroll
        for (int d = 1; d < 16; d <<= 1) {
            const int v = __shfl_up(wsc, d, 64);
            if (t >= d) wsc += v;
        }
        wsum[t] = wsc - ws;               // exclusive wave offset
        if (t == 15) off[NT] = wsc;       // grand total
    }
    __syncthreads();

    const int excl = wsum[wv] + (sc - sum);
    int4 o;
    o.x = excl;
    o.y = o.x + h.x;
    o.z = o.y + h.y;
    o.w = o.z + h.z;
    ((int4*)off)[t]    = o;
    ((int4*)cursor)[t] = o;
}

// ---------------------------------------------------------------------------
// Scatter (m,j,u) entries into u-tile-sorted order.
// ---------------------------------------------------------------------------
__global__ __launch_bounds__(256) void sort_kernel(
    const int* __restrict__ m0, const int* __restrict__ m1,
    const int* __restrict__ m2, int* __restrict__ cursor,
    int* __restrict__ sorted)
{
    const int total = MM * VV;
    for (int idx = blockIdx.x * 256 + threadIdx.x; idx < total;
         idx += gridDim.x * 256) {
        const int m = idx / VV;
        const int j = idx - m * VV;
        const int* mp = (m == 0) ? m0 : (m == 1) ? m1 : m2;
        const int u = mp[j];
        const int pos = atomicAdd(&cursor[u >> 4], 1);
        sorted[pos] = (j << 8) | (m << 6) | (u & 15);
    }
}

// ---------------------------------------------------------------------------
// Transpose + exp v2: ET[m][j][b] = (fp16) exp(logits[m][b][j]).
// Block = 64-j tile x ALL 256 b.  fp16 LDS tile [64][258] = 33 KB
// (4 blocks/CU).  Per-thread 4j x 4b register micro-tile:
//   - loads:  float4a along j   -> 16 insts/thread, 1 KB/wave/inst
//   - LDS wr: ds_write_b64 (4 halfs) -> 16 insts/thread
//   - LDS rd: ds_read_b64          -> 16 insts/thread (2-way, free)
//   - stores: dwordx2, 512 B/wave/inst FULLY coalesced (was 2 B/lane)
// FUSED Z row-sums: 4-step shfl_xor over each 16-lane j-group, one
// global fp32 atomic per (block,b) -> 786 adds/address (proven cheap).
// ---------------------------------------------------------------------------
__global__ __launch_bounds__(256) void transpose_exp2_kernel(
    const float* __restrict__ l0, const float* __restrict__ l1,
    const float* __restrict__ l2, _Float16* __restrict__ ET,
    float* __restrict__ Z)
{
    const int m  = blockIdx.y;
    const float* lg = (m == 0) ? l0 : (m == 1) ? l1 : l2;
    const int j0 = blockIdx.x * 64;

    __shared__ _Float16 tile[64][258];    // [j_local][b], +2 pad halfs

    const int t = threadIdx.x;
    const int l = t & 63;
    const int g = t & 15;                 // j-quad: j = j0 + 4g .. +3
    const int r = t >> 4;                 // b-range: b = 16r .. 16r+15

    const bool fullj = (j0 + 63) < VV;    // true for 785 of 786 tiles

    for (int sp = 0; sp < 4; ++sp) {
        const int bb = r * 16 + sp * 4;   // base b of this super-pass
        float e[4][4];                    // [q = b offset][c = j offset]
        if (fullj) {
            #pragma unroll
            for (int q = 0; q < 4; ++q) {
                const float4a v =
                    *(const float4a*)(lg + (size_t)(bb + q) * VV + j0 + 4 * g);
                e[q][0] = __expf(v.x); e[q][1] = __expf(v.y);
                e[q][2] = __expf(v.z); e[q][3] = __expf(v.w);
            }
        } else {
            #pragma unroll
            for (int q = 0; q < 4; ++q) {
                #pragma unroll
                for (int c = 0; c < 4; ++c) {
                    const int jc = j0 + 4 * g + c;
                    e[q][c] = (jc < VV)
                        ? __expf(lg[(size_t)(bb + q) * VV + jc]) : 0.0f;
                }
            }
        }
        // LDS: per j row, 4 consecutive b as one 8 B write
        #pragma unroll
        for (int c = 0; c < 4; ++c) {
            half4v hv;
            hv.x = (_Float16)e[0][c];
            hv.y = (_Float16)e[1][c];
            hv.z = (_Float16)e[2][c];
            hv.w = (_Float16)e[3][c];
            *(half4v*)&tile[4 * g + c][bb] = hv;
        }
        // fused Z: per q, reduce this thread's 4-j sum across the 16-lane
        // j-group (covers all 64 j of the tile), then one atomic.
        #pragma unroll
        for (int q = 0; q < 4; ++q) {
            float s = (e[q][0] + e[q][1]) + (e[q][2] + e[q][3]);
            s += __shfl_xor(s, 1, 64);
            s += __shfl_xor(s, 2, 64);
            s += __shfl_xor(s, 4, 64);
            s += __shfl_xor(s, 8, 64);
            if (g == 0) atomicAdd(&Z[m * BB + bb + q], s);
        }
    }
    __syncthreads();

    // store phase: wave wv handles 16 j rows; lane covers b = 4l..4l+3
    const int wv = t >> 6;
    #pragma unroll
    for (int it = 0; it < 16; ++it) {
        const int jj = wv * 16 + it;
        const int jw = j0 + jj;
        if (jw < VV) {
            const uint2 d = *(const uint2*)&tile[jj][4 * l];
            *(uint2*)(ET + ((size_t)m * VV + jw) * BB + 4 * l) = d;
        }
    }
}

// ---------------------------------------------------------------------------
// Accumulate v3 (unchanged from round 2 — dropped out of profile top-5):
// owner-computes, thread t owns batch column b=t, plain LDS add, no atomics.
// 16-slot tiles -> 16 KB LDS -> 8 blocks/CU; 8-deep pipelined entry loop.
// ---------------------------------------------------------------------------
__global__ __launch_bounds__(256, 8) void accumulate3_kernel(
    const _Float16* __restrict__ ET, const int* __restrict__ sorted,
    const int* __restrict__ off, const float* __restrict__ Z,
    const float* __restrict__ weights, float* __restrict__ out)
{
    const int k = blockIdx.x;             // u-tile
    const int t = threadIdx.x;            // b

    __shared__ float acc[TILE * 256];
    #pragma unroll
    for (int i = 0; i < TILE; ++i) acc[i * 256 + t] = 0.0f;
    const float w0 = weights[0] / Z[0 * BB + t];
    const float w1 = weights[1] / Z[1 * BB + t];
    const float w2 = weights[2] / Z[2 * BB + t];
    __syncthreads();

    const int s = off[k], e = off[k + 1];
    int i = s;
    for (; i + 8 <= e; i += 8) {
        int p[8];
        #pragma unroll
        for (int z = 0; z < 8; ++z) p[z] = sorted[i + z];   // uniform -> s_load
        float ev[8];
        #pragma unroll
        for (int z = 0; z < 8; ++z) {
            const int eoff = ((((p[z] >> 6) & 3) * VV + (p[z] >> 8)) << 8);
            ev[z] = (float)ET[eoff + t];                    // 8 loads in flight
        }
        #pragma unroll
        for (int z = 0; z < 8; ++z) {
            const int ul = p[z] & 15;
            const int m  = (p[z] >> 6) & 3;
            const float w = (m == 0) ? w0 : (m == 1) ? w1 : w2;
            acc[ul * 256 + (t ^ (2 * ul))] += w * ev[z];
        }
    }
    for (; i < e; ++i) {
        const int p = sorted[i];
        const int ul = p & 15;
        const int m  = (p >> 6) & 3;
        const int eoff = (((m * VV) + (p >> 8)) << 8);
        const float w = (m == 0) ? w0 : (m == 1) ? w1 : w2;
        acc[ul * 256 + (t ^ (2 * ul))] += w * (float)ET[eoff + t];
    }
    __syncthreads();

    const int u0   = k * TILE;
    const int slot = t & 15;
    const int q    = t >> 4;
    #pragma unroll
    for (int r = 0; r < 16; ++r) {
        const int b = r * 16 + q;
        out[(size_t)b * UU + u0 + slot] = acc[slot * 256 + (b ^ (2 * slot))];
    }
}

// ===========================================================================
// FALLBACK (proven round-2 path) — used only if ws_size < WS_NEED.
// ===========================================================================
#define FB_NBUCK 8
#define FB_BSZ   8192

__global__ __launch_bounds__(256) void fb_count_kernel(
    const int* __restrict__ m0, const int* __restrict__ m1,
    const int* __restrict__ m2, int* __restrict__ cnt)
{
    const int m = blockIdx.y;
    const int* mp = (m == 0) ? m0 : (m == 1) ? m1 : m2;
    __shared__ int hist[FB_NBUCK];
    if (threadIdx.x < FB_NBUCK) hist[threadIdx.x] = 0;
    __syncthreads();
    const int j = blockIdx.x * 256 + threadIdx.x;
    if (j < VV) atomicAdd(&hist[mp[j] >> 13], 1);
    __syncthreads();
    if (threadIdx.x < FB_NBUCK)
        atomicAdd(&cnt[m * FB_NBUCK + threadIdx.x], hist[threadIdx.x]);
}

__global__ void fb_prefix_kernel(const int* __restrict__ cnt,
                                 int* __restrict__ off, int* __restrict__ cursor)
{
    for (int m = 0; m < MM; ++m) {
        int acc = 0;
        for (int k = 0; k < FB_NBUCK; ++k) {
            off[m * (FB_NBUCK + 1) + k] = acc;
            cursor[m * FB_NBUCK + k]    = acc;
            acc += cnt[m * FB_NBUCK + k];
        }
        off[m * (FB_NBUCK + 1) + FB_NBUCK] = acc;
    }
}

__global__ __launch_bounds__(256) void fb_scatter_kernel(
    const int* __restrict__ m0, const int* __restrict__ m1,
    const int* __restrict__ m2, int* __restrict__ cursor,
    int* __restrict__ sorted)
{
    const int m = blockIdx.y;
    const int* mp = (m == 0) ? m0 : (m == 1) ? m1 : m2;
    int* srt = sorted + (size_t)m * VV;
    const int j = blockIdx.x * 256 + threadIdx.x;
    int u = 0, bucket = FB_NBUCK;
    if (j < VV) { u = mp[j]; bucket = u >> 13; }
    const int lane = threadIdx.x & 63;
    const unsigned long long lt = (1ull << lane) - 1ull;
    #pragma unroll
    for (int k = 0; k < FB_NBUCK; ++k) {
        unsigned long long mask = __ballot(bucket == k);
        if (mask) {
            int leader = __ffsll((long long)mask) - 1;
            int base = 0;
            if (lane == leader)
                base = atomicAdd(&cursor[m * FB_NBUCK + k], __popcll(mask));
            base = __shfl(base, leader, 64);
            if (bucket == k) {
                int pos = base + __popcll(mask & lt);
                srt[pos] = ((u & (FB_BSZ - 1)) << 16) | j;
            }
        }
    }
}

__global__ __launch_bounds__(512) void fb_accumulate_kernel(
    const float* __restrict__ l0, const float* __restrict__ l1,
    const float* __restrict__ l2,
    const int* __restrict__ sorted, const int* __restrict__ off,
    const float* __restrict__ winv, float* __restrict__ out)
{
    const int k = blockIdx.x;
    const int b = blockIdx.y;
    __shared__ float acc[FB_BSZ];
    for (int i = threadIdx.x; i < FB_BSZ; i += 512) acc[i] = 0.0f;
    __syncthreads();
    #pragma unroll
    for (int m = 0; m < MM; ++m) {
        const float* lg = (m == 0) ? l0 : (m == 1) ? l1 : l2;
        const float* row = lg + (size_t)b * VV;
        const int* srt = sorted + (size_t)m * VV;
        const float wv = winv[m * BB + b];
        const int s = off[m * (FB_NBUCK + 1) + k];
        const int e = off[m * (FB_NBUCK + 1) + k + 1];
        for (int i = s + threadIdx.x; i < e; i += 512) {
            const int pack = srt[i];
            atomicAdd(&acc[pack >> 16], wv * __expf(row[pack & 0xFFFF]));
        }
    }
    __syncthreads();
    float* orow = out + (size_t)b * UU + (size_t)k * FB_BSZ;
    for (int i = threadIdx.x; i < FB_BSZ; i += 512) orow[i] = acc[i];
}

// ---------------------------------------------------------------------------
extern "C" void kernel_launch(void* const* d_in, const int* in_sizes, int n_in,
                              void* d_out, int out_size, void* d_ws, size_t ws_size,
                              hipStream_t stream)
{
    const float* l0 = (const float*)d_in[0];
    const float* l1 = (const float*)d_in[1];
    const float* l2 = (const float*)d_in[2];
    const int*   m0 = (const int*)d_in[3];
    const int*   m1 = (const int*)d_in[4];
    const int*   m2 = (const int*)d_in[5];
    const float* w  = (const float*)d_in[6];
    float* out = (float*)d_out;
    char* ws = (char*)d_ws;

    if (ws_size >= WS_NEED) {
        float*    Z      = (float*)   (ws + WS_Z);
        int*      hist   = (int*)     (ws + WS_HIST);
        int*      off    = (int*)     (ws + WS_OFF);
        int*      cursor = (int*)     (ws + WS_CURSOR);
        int*      sorted = (int*)     (ws + WS_SORTED);
        _Float16* ET     = (_Float16*)(ws + WS_ET);

        // zero Z (3072 B) + hist (16384 B) in one shot
        hipMemsetAsync(ws, 0, WS_OFF, stream);

        hist_count_kernel<<<256, 256, 0, stream>>>(m0, m1, m2, hist);
        prefix_kernel<<<1, 1024, 0, stream>>>(hist, off, cursor);
        sort_kernel<<<256, 256, 0, stream>>>(m0, m1, m2, cursor, sorted);

        dim3 gtr((VV + 63) / 64, MM);               // (786, 3)
        transpose_exp2_kernel<<<gtr, 256, 0, stream>>>(l0, l1, l2, ET, Z);

        accumulate3_kernel<<<NT, 256, 0, stream>>>(ET, sorted, off, Z, w, out);
    } else {
        // round-2 fallback layout
        float* winv   = (float*)(ws + 0);
        int*   cnt    = (int*)  (ws + 3072);
        int*   off    = (int*)  (ws + 3200);
        int*   cursor = (int*)  (ws + 3456);
        int*   sorted = (int*)  (ws + 3584);

        hipMemsetAsync(cnt, 0, MM * FB_NBUCK * sizeof(int), stream);
        row_sums_kernel<<<MM * BB, 512, 0, stream>>>(l0, l1, l2, w, winv);
        dim3 gmap((VV + 255) / 256, MM);
        fb_count_kernel<<<gmap, 256, 0, stream>>>(m0, m1, m2, cnt);
        fb_prefix_kernel<<<1, 1, 0, stream>>>(cnt, off, cursor);
        fb_scatter_kernel<<<gmap, 256, 0, stream>>>(m0, m1, m2, cursor, sorted);
        dim3 gacc(FB_NBUCK, BB);
        fb_accumulate_kernel<<<gacc, 512, 0, stream>>>(l0, l1, l2, sorted, off, winv, out);
    }
}

// Round 4
// 286.879 us; speedup vs baseline: 2.3924x; 2.3924x over previous
//
#include <hip/hip_runtime.h>

// Problem constants
#define BB 256      // batch
#define VV 50257    // per-model vocab
#define UU 65536    // union vocab
#define MM 3        // models
#define TILE 16     // u-tile width (union slots per accumulate block)
#define NT 4096     // u-tiles (UU / TILE)

typedef float float4a __attribute__((ext_vector_type(4), aligned(4)));
typedef _Float16 half4v __attribute__((ext_vector_type(4)));

// ---------------------------------------------------------------------------
// FAST-PATH workspace layout (bytes):
//   0      : Z      [3*256] float  (softmax denominators; memset 0 each call)
//   3072   : hist   [4096]  int    (memset 0 each call)
//   19456  : off    [4097]  int
//   35856  : cursor [4096]  int    (16-aligned for int4 stores)
//   52240  : sorted [150771] int   (packed (j<<8)|(m<<6)|(u&15))
//   655360 : ET     [3][50257][256] fp16  (77,194,752 B)
// total 77,850,112 B
// ---------------------------------------------------------------------------
#define WS_Z      0
#define WS_HIST   3072
#define WS_OFF    19456
#define WS_CURSOR 35856
#define WS_SORTED 52240
#define WS_ET     655360
#define WS_NEED   77850112ull

// ---------------------------------------------------------------------------
// winv[m*B+b] = w_m / sum_j exp(logits[m][b][j]).  FALLBACK PATH ONLY.
// ---------------------------------------------------------------------------
__global__ __launch_bounds__(512) void row_sums_kernel(
    const float* __restrict__ l0, const float* __restrict__ l1,
    const float* __restrict__ l2, const float* __restrict__ weights,
    float* __restrict__ winv)
{
    const int bx = blockIdx.x;            // [0, MM*BB)
    const int m  = bx >> 8;
    const int b  = bx & 255;
    const float* lg  = (m == 0) ? l0 : (m == 1) ? l1 : l2;
    const float* row = lg + (size_t)b * VV;
    const float4a* rowv = (const float4a*)row;

    const int nv4 = VV / 4;               // 12564, tail element j=50256
    float partial = 0.0f;
    for (int i = threadIdx.x; i < nv4; i += 512) {
        float4a v = rowv[i];
        partial += __expf(v.x) + __expf(v.y) + __expf(v.z) + __expf(v.w);
    }
    if (threadIdx.x == 0) partial += __expf(row[VV - 1]);

    #pragma unroll
    for (int off = 32; off > 0; off >>= 1)
        partial += __shfl_down(partial, off, 64);

    __shared__ float smem[8];
    const int lane = threadIdx.x & 63;
    const int wv   = threadIdx.x >> 6;
    if (lane == 0) smem[wv] = partial;
    __syncthreads();
    if (threadIdx.x == 0) {
        float tot = 0.0f;
        #pragma unroll
        for (int w = 0; w < 8; ++w) tot += smem[w];
        winv[bx] = weights[m] / tot;
    }
}

// ---------------------------------------------------------------------------
// u-tile histogram over all 3 maps.  Direct global int atomics (native
// global_atomic_add_u32): 150,771 atomics over 4096 bins ~ 37/bin.
// ---------------------------------------------------------------------------
__global__ __launch_bounds__(256) void hist_count_kernel(
    const int* __restrict__ m0, const int* __restrict__ m1,
    const int* __restrict__ m2, int* __restrict__ hist)
{
    const int total = MM * VV;
    for (int idx = blockIdx.x * 256 + threadIdx.x; idx < total;
         idx += gridDim.x * 256) {
        const int m = idx / VV;           // const divisor -> magic mul
        const int j = idx - m * VV;
        const int* mp = (m == 0) ? m0 : (m == 1) ? m1 : m2;
        atomicAdd(&hist[mp[j] >> 4], 1);
    }
}

// ---------------------------------------------------------------------------
// Single-block exclusive scan over 4096 bins.
// shfl wave-scan (6 steps) + 16-wave-sum scan -> 2 barriers total.
// ---------------------------------------------------------------------------
__global__ __launch_bounds__(1024) void prefix_kernel(
    const int* __restrict__ hist, int* __restrict__ off, int* __restrict__ cursor)
{
    __shared__ int wsum[16];
    const int t = threadIdx.x;
    const int l = t & 63, wv = t >> 6;
    const int4 h = ((const int4*)hist)[t];        // bins 4t..4t+3
    const int sum = h.x + h.y + h.z + h.w;

    // inclusive wave scan of per-thread sums
    int sc = sum;
    #pragma unroll
    for (int d = 1; d < 64; d <<= 1) {
        const int v = __shfl_up(sc, d, 64);
        if (l >= d) sc += v;
    }
    if (l == 63) wsum[wv] = sc;
    __syncthreads();
    if (t < 16) {
        const int ws = wsum[t];
        int wsc = ws;
        #pragma unroll
        for (int d = 1; d < 16; d <<= 1) {
            const int v = __shfl_up(wsc, d, 64);
            if (t >= d) wsc += v;
        }
        wsum[t] = wsc - ws;               // exclusive wave offset
        if (t == 15) off[NT] = wsc;       // grand total
    }
    __syncthreads();

    const int excl = wsum[wv] + (sc - sum);
    int4 o;
    o.x = excl;
    o.y = o.x + h.x;
    o.z = o.y + h.y;
    o.w = o.z + h.z;
    ((int4*)off)[t]    = o;
    ((int4*)cursor)[t] = o;
}

// ---------------------------------------------------------------------------
// Scatter (m,j,u) entries into u-tile-sorted order.
// ---------------------------------------------------------------------------
__global__ __launch_bounds__(256) void sort_kernel(
    const int* __restrict__ m0, const int* __restrict__ m1,
    const int* __restrict__ m2, int* __restrict__ cursor,
    int* __restrict__ sorted)
{
    const int total = MM * VV;
    for (int idx = blockIdx.x * 256 + threadIdx.x; idx < total;
         idx += gridDim.x * 256) {
        const int m = idx / VV;
        const int j = idx - m * VV;
        const int* mp = (m == 0) ? m0 : (m == 1) ? m1 : m2;
        const int u = mp[j];
        const int pos = atomicAdd(&cursor[u >> 4], 1);
        sorted[pos] = (j << 8) | (m << 6) | (u & 15);
    }
}

// ---------------------------------------------------------------------------
// Transpose + exp v3: ET[m][j][b] = (fp16) exp(logits[m][b][j]).
// Round-3 structure (float4 loads / b64 LDS / dwordx2 stores) with the two
// diagnosed defects fixed:
//   (a) NO mid-loop global fp32 atomics (the 494 us CAS retry storm, +16.5MB
//       WRITE_SIZE).  Z accumulates in registers zs[16]; end-of-kernel LDS
//       reduce + 4 per-lane-distinct atomic insts/block = 9,432 total =
//       exactly round 2's proven zero-retry pattern & summation tree.
//   (b) LDS tile [64][256] fp16 (32 KB, 5 blocks/CU) with XOR cell swizzle
//       phys_cell = cell ^ (row>>2): both write and read instructions hit
//       each bank with exactly 4 dwords = the b64 conflict floor (the old
//       [64][258] pad mis-aligned b64 and collapsed g onto 4 banks).
// ---------------------------------------------------------------------------
__global__ __launch_bounds__(256) void transpose_exp3_kernel(
    const float* __restrict__ l0, const float* __restrict__ l1,
    const float* __restrict__ l2, _Float16* __restrict__ ET,
    float* __restrict__ Z)
{
    const int m  = blockIdx.y;
    const float* lg = (m == 0) ? l0 : (m == 1) ? l1 : l2;
    const int j0 = blockIdx.x * 64;

    __shared__ _Float16 tile[64][256];    // XOR-swizzled in 8 B (4-half) cells

    const int t = threadIdx.x;
    const int l = t & 63;
    const int g = t & 15;                 // j-quad: j = j0 + 4g .. +3
    const int r = t >> 4;                 // b-range: b = 16r .. 16r+15

    const bool fullj = (j0 + 63) < VV;    // true for 785 of 786 tiles

    float zs[16];                          // per-thread Z partials, b=16r+idx
    #pragma unroll
    for (int i = 0; i < 16; ++i) zs[i] = 0.0f;

    #pragma unroll                        // sp MUST be compile-time (rule #20)
    for (int sp = 0; sp < 4; ++sp) {
        const int bb = r * 16 + sp * 4;   // base b of this super-pass
        float e[4][4];                    // [q = b offset][c = j offset]
        if (fullj) {
            #pragma unroll
            for (int q = 0; q < 4; ++q) {
                const float4a v =
                    *(const float4a*)(lg + (size_t)(bb + q) * VV + j0 + 4 * g);
                e[q][0] = __expf(v.x); e[q][1] = __expf(v.y);
                e[q][2] = __expf(v.z); e[q][3] = __expf(v.w);
            }
        } else {
            #pragma unroll
            for (int q = 0; q < 4; ++q) {
                #pragma unroll
                for (int c = 0; c < 4; ++c) {
                    const int jc = j0 + 4 * g + c;
                    e[q][c] = (jc < VV)
                        ? __expf(lg[(size_t)(bb + q) * VV + jc]) : 0.0f;
                }
            }
        }
        // LDS: row = 4g+c, swizzled cell (4r+sp)^g, one 8 B write per c
        const int pc = (4 * r + sp) ^ g;
        #pragma unroll
        for (int c = 0; c < 4; ++c) {
            half4v hv;
            hv.x = (_Float16)e[0][c];
            hv.y = (_Float16)e[1][c];
            hv.z = (_Float16)e[2][c];
            hv.w = (_Float16)e[3][c];
            *(half4v*)&tile[4 * g + c][pc * 4] = hv;
        }
        // register Z accumulation (no memory traffic)
        #pragma unroll
        for (int q = 0; q < 4; ++q)
            zs[sp * 4 + q] += (e[q][0] + e[q][1]) + (e[q][2] + e[q][3]);
    }
    __syncthreads();

    // store phase: wave wv handles 16 j rows; lane covers b = 4l..4l+3
    const int wv = t >> 6;
    #pragma unroll
    for (int it = 0; it < 16; ++it) {
        const int jj = wv * 16 + it;
        const int jw = j0 + jj;
        if (jw < VV) {
            const uint2 d = *(const uint2*)&tile[jj][(l ^ (jj >> 2)) * 4];
            *(uint2*)(ET + ((size_t)m * VV + jw) * BB + 4 * l) = d;
        }
    }
    __syncthreads();

    // Z reduce: reuse tile as fp32 scratch [g][256], then 4 atomic insts
    // (threads 0..255, per-lane-distinct addresses -> zero-retry pattern).
    float* zsc = (float*)&tile[0][0];     // 8192 floats available, 4096 used
    #pragma unroll
    for (int q = 0; q < 4; ++q) {
        float4a v;
        v.x = zs[4 * q + 0]; v.y = zs[4 * q + 1];
        v.z = zs[4 * q + 2]; v.w = zs[4 * q + 3];
        ((float4a*)(zsc + g * 256 + 16 * r))[q] = v;
    }
    __syncthreads();
    float s = 0.0f;
    #pragma unroll
    for (int gg = 0; gg < 16; ++gg) s += zsc[gg * 256 + t];
    atomicAdd(&Z[m * BB + t], s);
}

// ---------------------------------------------------------------------------
// Accumulate v3 (unchanged — dropped out of profile top-5 in rounds 2-3):
// owner-computes, thread t owns batch column b=t, plain LDS add, no atomics.
// 16-slot tiles -> 16 KB LDS -> 8 blocks/CU; 8-deep pipelined entry loop.
// ---------------------------------------------------------------------------
__global__ __launch_bounds__(256, 8) void accumulate3_kernel(
    const _Float16* __restrict__ ET, const int* __restrict__ sorted,
    const int* __restrict__ off, const float* __restrict__ Z,
    const float* __restrict__ weights, float* __restrict__ out)
{
    const int k = blockIdx.x;             // u-tile
    const int t = threadIdx.x;            // b

    __shared__ float acc[TILE * 256];
    #pragma unroll
    for (int i = 0; i < TILE; ++i) acc[i * 256 + t] = 0.0f;
    const float w0 = weights[0] / Z[0 * BB + t];
    const float w1 = weights[1] / Z[1 * BB + t];
    const float w2 = weights[2] / Z[2 * BB + t];
    __syncthreads();

    const int s = off[k], e = off[k + 1];
    int i = s;
    for (; i + 8 <= e; i += 8) {
        int p[8];
        #pragma unroll
        for (int z = 0; z < 8; ++z) p[z] = sorted[i + z];   // uniform -> s_load
        float ev[8];
        #pragma unroll
        for (int z = 0; z < 8; ++z) {
            const int eoff = ((((p[z] >> 6) & 3) * VV + (p[z] >> 8)) << 8);
            ev[z] = (float)ET[eoff + t];                    // 8 loads in flight
        }
        #pragma unroll
        for (int z = 0; z < 8; ++z) {
            const int ul = p[z] & 15;
            const int m  = (p[z] >> 6) & 3;
            const float w = (m == 0) ? w0 : (m == 1) ? w1 : w2;
            acc[ul * 256 + (t ^ (2 * ul))] += w * ev[z];
        }
    }
    for (; i < e; ++i) {
        const int p = sorted[i];
        const int ul = p & 15;
        const int m  = (p >> 6) & 3;
        const int eoff = (((m * VV) + (p >> 8)) << 8);
        const float w = (m == 0) ? w0 : (m == 1) ? w1 : w2;
        acc[ul * 256 + (t ^ (2 * ul))] += w * (float)ET[eoff + t];
    }
    __syncthreads();

    const int u0   = k * TILE;
    const int slot = t & 15;
    const int q    = t >> 4;
    #pragma unroll
    for (int r = 0; r < 16; ++r) {
        const int b = r * 16 + q;
        out[(size_t)b * UU + u0 + slot] = acc[slot * 256 + (b ^ (2 * slot))];
    }
}

// ===========================================================================
// FALLBACK (proven round-2 path) — used only if ws_size < WS_NEED.
// ===========================================================================
#define FB_NBUCK 8
#define FB_BSZ   8192

__global__ __launch_bounds__(256) void fb_count_kernel(
    const int* __restrict__ m0, const int* __restrict__ m1,
    const int* __restrict__ m2, int* __restrict__ cnt)
{
    const int m = blockIdx.y;
    const int* mp = (m == 0) ? m0 : (m == 1) ? m1 : m2;
    __shared__ int hist[FB_NBUCK];
    if (threadIdx.x < FB_NBUCK) hist[threadIdx.x] = 0;
    __syncthreads();
    const int j = blockIdx.x * 256 + threadIdx.x;
    if (j < VV) atomicAdd(&hist[mp[j] >> 13], 1);
    __syncthreads();
    if (threadIdx.x < FB_NBUCK)
        atomicAdd(&cnt[m * FB_NBUCK + threadIdx.x], hist[threadIdx.x]);
}

__global__ void fb_prefix_kernel(const int* __restrict__ cnt,
                                 int* __restrict__ off, int* __restrict__ cursor)
{
    for (int m = 0; m < MM; ++m) {
        int acc = 0;
        for (int k = 0; k < FB_NBUCK; ++k) {
            off[m * (FB_NBUCK + 1) + k] = acc;
            cursor[m * FB_NBUCK + k]    = acc;
            acc += cnt[m * FB_NBUCK + k];
        }
        off[m * (FB_NBUCK + 1) + FB_NBUCK] = acc;
    }
}

__global__ __launch_bounds__(256) void fb_scatter_kernel(
    const int* __restrict__ m0, const int* __restrict__ m1,
    const int* __restrict__ m2, int* __restrict__ cursor,
    int* __restrict__ sorted)
{
    const int m = blockIdx.y;
    const int* mp = (m == 0) ? m0 : (m == 1) ? m1 : m2;
    int* srt = sorted + (size_t)m * VV;
    const int j = blockIdx.x * 256 + threadIdx.x;
    int u = 0, bucket = FB_NBUCK;
    if (j < VV) { u = mp[j]; bucket = u >> 13; }
    const int lane = threadIdx.x & 63;
    const unsigned long long lt = (1ull << lane) - 1ull;
    #pragma unroll
    for (int k = 0; k < FB_NBUCK; ++k) {
        unsigned long long mask = __ballot(bucket == k);
        if (mask) {
            int leader = __ffsll((long long)mask) - 1;
            int base = 0;
            if (lane == leader)
                base = atomicAdd(&cursor[m * FB_NBUCK + k], __popcll(mask));
            base = __shfl(base, leader, 64);
            if (bucket == k) {
                int pos = base + __popcll(mask & lt);
                srt[pos] = ((u & (FB_BSZ - 1)) << 16) | j;
            }
        }
    }
}

__global__ __launch_bounds__(512) void fb_accumulate_kernel(
    const float* __restrict__ l0, const float* __restrict__ l1,
    const float* __restrict__ l2,
    const int* __restrict__ sorted, const int* __restrict__ off,
    const float* __restrict__ winv, float* __restrict__ out)
{
    const int k = blockIdx.x;
    const int b = blockIdx.y;
    __shared__ float acc[FB_BSZ];
    for (int i = threadIdx.x; i < FB_BSZ; i += 512) acc[i] = 0.0f;
    __syncthreads();
    #pragma unroll
    for (int m = 0; m < MM; ++m) {
        const float* lg = (m == 0) ? l0 : (m == 1) ? l1 : l2;
        const float* row = lg + (size_t)b * VV;
        const int* srt = sorted + (size_t)m * VV;
        const float wv = winv[m * BB + b];
        const int s = off[m * (FB_NBUCK + 1) + k];
        const int e = off[m * (FB_NBUCK + 1) + k + 1];
        for (int i = s + threadIdx.x; i < e; i += 512) {
            const int pack = srt[i];
            atomicAdd(&acc[pack >> 16], wv * __expf(row[pack & 0xFFFF]));
        }
    }
    __syncthreads();
    float* orow = out + (size_t)b * UU + (size_t)k * FB_BSZ;
    for (int i = threadIdx.x; i < FB_BSZ; i += 512) orow[i] = acc[i];
}

// ---------------------------------------------------------------------------
extern "C" void kernel_launch(void* const* d_in, const int* in_sizes, int n_in,
                              void* d_out, int out_size, void* d_ws, size_t ws_size,
                              hipStream_t stream)
{
    const float* l0 = (const float*)d_in[0];
    const float* l1 = (const float*)d_in[1];
    const float* l2 = (const float*)d_in[2];
    const int*   m0 = (const int*)d_in[3];
    const int*   m1 = (const int*)d_in[4];
    const int*   m2 = (const int*)d_in[5];
    const float* w  = (const float*)d_in[6];
    float* out = (float*)d_out;
    char* ws = (char*)d_ws;

    if (ws_size >= WS_NEED) {
        float*    Z      = (float*)   (ws + WS_Z);
        int*      hist   = (int*)     (ws + WS_HIST);
        int*      off    = (int*)     (ws + WS_OFF);
        int*      cursor = (int*)     (ws + WS_CURSOR);
        int*      sorted = (int*)     (ws + WS_SORTED);
        _Float16* ET     = (_Float16*)(ws + WS_ET);

        // zero Z (3072 B) + hist (16384 B) in one shot
        hipMemsetAsync(ws, 0, WS_OFF, stream);

        hist_count_kernel<<<256, 256, 0, stream>>>(m0, m1, m2, hist);
        prefix_kernel<<<1, 1024, 0, stream>>>(hist, off, cursor);
        sort_kernel<<<256, 256, 0, stream>>>(m0, m1, m2, cursor, sorted);

        dim3 gtr((VV + 63) / 64, MM);               // (786, 3)
        transpose_exp3_kernel<<<gtr, 256, 0, stream>>>(l0, l1, l2, ET, Z);

        accumulate3_kernel<<<NT, 256, 0, stream>>>(ET, sorted, off, Z, w, out);
    } else {
        // round-2 fallback layout
        float* winv   = (float*)(ws + 0);
        int*   cnt    = (int*)  (ws + 3072);
        int*   off    = (int*)  (ws + 3200);
        int*   cursor = (int*)  (ws + 3456);
        int*   sorted = (int*)  (ws + 3584);

        hipMemsetAsync(cnt, 0, MM * FB_NBUCK * sizeof(int), stream);
        row_sums_kernel<<<MM * BB, 512, 0, stream>>>(l0, l1, l2, w, winv);
        dim3 gmap((VV + 255) / 256, MM);
        fb_count_kernel<<<gmap, 256, 0, stream>>>(m0, m1, m2, cnt);
        fb_prefix_kernel<<<1, 1, 0, stream>>>(cnt, off, cursor);
        fb_scatter_kernel<<<gmap, 256, 0, stream>>>(m0, m1, m2, cursor, sorted);
        dim3 gacc(FB_NBUCK, BB);
        fb_accumulate_kernel<<<gacc, 512, 0, stream>>>(l0, l1, l2, sorted, off, winv, out);
    }
}